// Round 12
// baseline (1406.358 us; speedup 1.0000x reference)
//
#include <hip/hip_runtime.h>

#define NN 20000
#define DEG 16
#define HDIM 128
#define GDIM 512

typedef __attribute__((ext_vector_type(8))) short bf16x8;
typedef __attribute__((ext_vector_type(4))) float f32x4;
typedef __attribute__((ext_vector_type(2))) unsigned u32x2;
typedef __attribute__((ext_vector_type(4))) unsigned u32x4;
typedef unsigned long long ull;

#define L2E  1.4426950408889634f
#define L2E2 2.8853900817779268f

__device__ __forceinline__ f32x4 mfma16(bf16x8 a, bf16x8 b, f32x4 c) {
    return __builtin_amdgcn_mfma_f32_16x16x32_bf16(a, b, c, 0, 0, 0);
}

__device__ __forceinline__ unsigned short f2bf(float f) {
    unsigned u = __builtin_bit_cast(unsigned, f);
    u += 0x7FFFu + ((u >> 16) & 1u);
    return (unsigned short)(u >> 16);
}

__device__ __forceinline__ unsigned cvtpk(float lo, float hi) {
    unsigned r;
    asm("v_cvt_pk_bf16_f32 %0, %1, %2" : "=v"(r) : "v"(lo), "v"(hi));
    return r;
}

__device__ __forceinline__ float bfhi(unsigned u) { return __builtin_bit_cast(float, u & 0xFFFF0000u); }
__device__ __forceinline__ float bflo(unsigned u) { return __builtin_bit_cast(float, u << 16); }

__device__ __forceinline__ void barrier_lgkm() {
    asm volatile("s_waitcnt lgkmcnt(0)\ns_barrier" ::: "memory");
}

__device__ __forceinline__ float sig_pre(float x) {     // x pre-scaled by log2e
    return __builtin_amdgcn_rcpf(1.f + __builtin_amdgcn_exp2f(-x));
}
__device__ __forceinline__ float tanh_pre2(float x2) {  // x2 pre-scaled by 2*log2e
    return 1.f - 2.f * __builtin_amdgcn_rcpf(__builtin_amdgcn_exp2f(x2) + 1.f);
}

// ---------------- weight convert + combined bias ----------------------------
// dhh is emitted in FRAGMENT-CONTIGUOUS layout: for thread identity (col,qh),
// its 16 bf16x8 fragments (g,kt) live at consecutive offsets
//   dhh[(col*4+qh)*128 + (g*4+kt)*8 + j]
// so the lstm kernel loads all 16 with ONE vaddr + imm offsets 0..240B.
struct CvtArgs {
    const float *wih[3], *whh[3], *wl[3], *wr[3], *bih[3], *bhh[3];
    unsigned short *dih[3], *dhh[3], *dl[3], *dr[3];
    float *dbias[3];
};

__global__ __launch_bounds__(256) void cvt_kernel(CvtArgs a) {
    int l = blockIdx.x / 642, b = blockIdx.x % 642, t = threadIdx.x;
    if (b < 256) {
        int i = b * 256 + t;
        float s = ((i >> 14) == 2) ? L2E2 : L2E;
        a.dih[l][i] = f2bf(a.wih[l][i] * s);
    } else if (b < 512) {                // w_hh -> fragment-contiguous
        int o = (b - 256) * 256 + t;
        int j = o & 7, kt = (o >> 3) & 3, g = (o >> 5) & 3;
        int qh = (o >> 7) & 3, col = (o >> 9) & 127;
        float s = (g == 2) ? L2E2 : L2E;
        a.dhh[l][o] = f2bf(a.whh[l][(g * 128 + col) * 128 + kt * 32 + qh * 8 + j] * s);
    } else if (b < 576) {
        int i = (b - 512) * 256 + t;
        a.dl[l][i] = f2bf(a.wl[l][i]);
    } else if (b < 640) {
        int i = (b - 576) * 256 + t;
        a.dr[l][i] = f2bf(a.wr[l][i]);
    } else {
        int i = (b - 640) * 256 + t;
        float s = ((i >> 7) == 2) ? L2E2 : L2E;
        a.dbias[l][i] = (a.bih[l][i] + a.bhh[l][i]) * s;
    }
}

// ---- phase A (32-node tile): Xih from htile, interleaved bf16 out ----------
__device__ __forceinline__ void phaseA2(const unsigned short (*htile)[136],
        const unsigned short* __restrict__ wih, const float* __restrict__ biasc,
        unsigned short* __restrict__ xihb, int mbase, int cl, int qh, int k8, int wv) {
    bf16x8 a0[4], a1[4];
#pragma unroll
    for (int kt = 0; kt < 4; ++kt) {
        a0[kt] = *(const bf16x8*)(&htile[cl][kt * 32 + k8]);
        a1[kt] = *(const bf16x8*)(&htile[16 + cl][kt * 32 + k8]);
    }
#pragma unroll
    for (int nt = 0; nt < 2; ++nt) {
        const int col = wv * 32 + nt * 16 + cl;
        f32x4 acc0[4], acc1[4];
#pragma unroll
        for (int g = 0; g < 4; ++g) {
            acc0[g] = (f32x4){0.f, 0.f, 0.f, 0.f};
            acc1[g] = (f32x4){0.f, 0.f, 0.f, 0.f};
        }
#pragma unroll
        for (int g = 0; g < 4; ++g)
#pragma unroll
            for (int kt = 0; kt < 4; ++kt) {
                bf16x8 b = *(const bf16x8*)(wih + (g * 128 + col) * HDIM + kt * 32 + k8);
                acc0[g] = mfma16(a0[kt], b, acc0[g]);
                acc1[g] = mfma16(a1[kt], b, acc1[g]);
            }
        float bias[4];
#pragma unroll
        for (int g = 0; g < 4; ++g) bias[g] = biasc[g * 128 + col];
#pragma unroll
        for (int r = 0; r < 4; ++r) {
            unsigned p0 = cvtpk(acc0[0][r] + bias[0], acc0[1][r] + bias[1]);
            unsigned p1 = cvtpk(acc0[2][r] + bias[2], acc0[3][r] + bias[3]);
            *(ull*)(xihb + (size_t)(mbase + qh * 4 + r) * GDIM + col * 4) =
                (ull)p0 | ((ull)p1 << 32);
            unsigned q0 = cvtpk(acc1[0][r] + bias[0], acc1[1][r] + bias[1]);
            unsigned q1 = cvtpk(acc1[2][r] + bias[2], acc1[3][r] + bias[3]);
            *(ull*)(xihb + (size_t)(mbase + 16 + qh * 4 + r) * GDIM + col * 4) =
                (ull)q0 | ((ull)q1 << 32);
        }
    }
}

// ---- gemmA0: h0 = concat(x, emb[type]) (bf16) + Xih layer 0, 32 nodes ------
__global__ __launch_bounds__(256) void gemmA0_kernel(
        const float* __restrict__ x, const int* __restrict__ types,
        const float* __restrict__ emb, const unsigned short* __restrict__ wih,
        const float* __restrict__ biasc, unsigned short* __restrict__ h0,
        unsigned short* __restrict__ xihb) {
    __shared__ unsigned short htile[32][136];
    const int tid = threadIdx.x;
    const int lane = tid & 63, wv = tid >> 6;
    const int cl = lane & 15, qh = lane >> 4, k8 = qh * 8;
    const int mbase = blockIdx.x * 32;

    const int row = tid >> 3, c0 = (tid & 7) * 16;
    f32x4 u[4];
    if (c0 < 96) {
#pragma unroll
        for (int j = 0; j < 4; ++j)
            u[j] = *(const f32x4*)(x + (size_t)(mbase + row) * 96 + c0 + 4 * j);
    } else {
        int ty = types[mbase + row];
#pragma unroll
        for (int j = 0; j < 4; ++j)
            u[j] = *(const f32x4*)(emb + ty * 32 + (c0 - 96) + 4 * j);
    }
    u32x4 pk, pk2;
    pk[0]  = cvtpk(u[0][0], u[0][1]); pk[1]  = cvtpk(u[0][2], u[0][3]);
    pk[2]  = cvtpk(u[1][0], u[1][1]); pk[3]  = cvtpk(u[1][2], u[1][3]);
    pk2[0] = cvtpk(u[2][0], u[2][1]); pk2[1] = cvtpk(u[2][2], u[2][3]);
    pk2[2] = cvtpk(u[3][0], u[3][1]); pk2[3] = cvtpk(u[3][2], u[3][3]);
    *(u32x4*)(&htile[row][c0]) = pk;
    *(u32x4*)(&htile[row][c0 + 8]) = pk2;
    *(u32x4*)(h0 + (size_t)(mbase + row) * HDIM + c0) = pk;
    *(u32x4*)(h0 + (size_t)(mbase + row) * HDIM + c0 + 8) = pk2;
    __syncthreads();

    phaseA2(htile, wih, biasc, xihb, mbase, cl, qh, k8, wv);
}

// ---------------- fused per-node LSTM ---------------------------------------
// 512 threads / 8 waves, 16 nodes/block — proven round-7 skeleton. Changes:
// (1) launch_bounds(512,3): 170-VGPR cap so the ~70-reg live set fits with
//     no per-step scratch spill, while allocator can still target 3 waves/EU
//     (parity with today's achieved occupancy).
// (2) whh in fragment-contiguous layout: 16 loads/step from ONE vaddr with
//     imm offsets 0..240, issued at the TOP of each step so the MFMA's
//     vmcnt wait retires them while younger gather prefetches stay in flight.
__global__ __launch_bounds__(512, 3) void lstm_kernel(
        const unsigned short* __restrict__ xihb, const unsigned short* __restrict__ whhf,
        const int* __restrict__ esrc, unsigned short* __restrict__ agg) {
    __shared__ unsigned short hbuf[2][16][136];   // +8 pad
    __shared__ unsigned srcs_t[256];              // [t][node], pre-shifted <<10

    const int tid = threadIdx.x;
    const int lane = tid & 63, wv = tid >> 6;
    const int cl = lane & 15, qh = lane >> 4, k8 = qh * 8;
    const int colb = wv * 16 + cl;
    const int base = blockIdx.x * 16;

    if (tid < 256)
        srcs_t[(tid & 15) * 16 + (tid >> 4)] = ((unsigned)esrc[base * DEG + tid]) << 10;
    __syncthreads();

    const unsigned short* wp = whhf + (size_t)(colb * 4 + qh) * 128;  // 16 frags, 256B
    const char* xp = (const char*)xihb + (size_t)colb * 8u;
    float c0 = 0.f, c1 = 0.f, c2 = 0.f, c3 = 0.f;
    unsigned pk0 = 0, pk1 = 0;
    ull xa0, xa1, xa2, xa3, xb0, xb1, xb2, xb3;

#define GATH(T, X0, X1, X2, X3) { \
    u32x4 sv = *(const u32x4*)&srcs_t[(T) * 16 + qh * 4]; \
    X0 = *(const ull*)(xp + sv[0]); \
    X1 = *(const ull*)(xp + sv[1]); \
    X2 = *(const ull*)(xp + sv[2]); \
    X3 = *(const ull*)(xp + sv[3]); }

    GATH(0, xa0, xa1, xa2, xa3)
    GATH(1, xb0, xb1, xb2, xb3)

#define STEP(T, X0, X1, X2, X3) { \
    bf16x8 w00, w01, w02, w03, w10, w11, w12, w13, \
           w20, w21, w22, w23, w30, w31, w32, w33; \
    if ((T) > 0) {                      /* issue whh loads FIRST (oldest vmem) */ \
        w00 = *(const bf16x8*)(wp +   0); w01 = *(const bf16x8*)(wp +   8); \
        w02 = *(const bf16x8*)(wp +  16); w03 = *(const bf16x8*)(wp +  24); \
        w10 = *(const bf16x8*)(wp +  32); w11 = *(const bf16x8*)(wp +  40); \
        w12 = *(const bf16x8*)(wp +  48); w13 = *(const bf16x8*)(wp +  56); \
        w20 = *(const bf16x8*)(wp +  64); w21 = *(const bf16x8*)(wp +  72); \
        w22 = *(const bf16x8*)(wp +  80); w23 = *(const bf16x8*)(wp +  88); \
        w30 = *(const bf16x8*)(wp +  96); w31 = *(const bf16x8*)(wp + 104); \
        w32 = *(const bf16x8*)(wp + 112); w33 = *(const bf16x8*)(wp + 120); \
    } \
    f32x4 a0, a1, a2, a3; \
    { unsigned lo = (unsigned)X0, hi = (unsigned)(X0 >> 32); \
      a0[0] = bflo(lo); a1[0] = bfhi(lo); a2[0] = bflo(hi); a3[0] = bfhi(hi); } \
    { unsigned lo = (unsigned)X1, hi = (unsigned)(X1 >> 32); \
      a0[1] = bflo(lo); a1[1] = bfhi(lo); a2[1] = bflo(hi); a3[1] = bfhi(hi); } \
    { unsigned lo = (unsigned)X2, hi = (unsigned)(X2 >> 32); \
      a0[2] = bflo(lo); a1[2] = bfhi(lo); a2[2] = bflo(hi); a3[2] = bfhi(hi); } \
    { unsigned lo = (unsigned)X3, hi = (unsigned)(X3 >> 32); \
      a0[3] = bflo(lo); a1[3] = bfhi(lo); a2[3] = bflo(hi); a3[3] = bfhi(hi); } \
    if ((T) < 14) { GATH((T) + 2, X0, X1, X2, X3) } \
    if ((T) > 0) { \
        const unsigned short* hrow = &hbuf[((T) + 1) & 1][cl][k8]; \
        bf16x8 h0 = *(const bf16x8*)(hrow); \
        bf16x8 h1 = *(const bf16x8*)(hrow + 32); \
        bf16x8 h2 = *(const bf16x8*)(hrow + 64); \
        bf16x8 h3 = *(const bf16x8*)(hrow + 96); \
        a0 = mfma16(h0, w00, a0); a0 = mfma16(h1, w01, a0); \
        a0 = mfma16(h2, w02, a0); a0 = mfma16(h3, w03, a0); \
        a1 = mfma16(h0, w10, a1); a1 = mfma16(h1, w11, a1); \
        a1 = mfma16(h2, w12, a1); a1 = mfma16(h3, w13, a1); \
        a2 = mfma16(h0, w20, a2); a2 = mfma16(h1, w21, a2); \
        a2 = mfma16(h2, w22, a2); a2 = mfma16(h3, w23, a2); \
        a3 = mfma16(h0, w30, a3); a3 = mfma16(h1, w31, a3); \
        a3 = mfma16(h2, w32, a3); a3 = mfma16(h3, w33, a3); \
    } \
    float i0 = sig_pre(a0[0]), f0 = sig_pre(a1[0]), g0 = tanh_pre2(a2[0]), o0 = sig_pre(a3[0]); \
    c0 = f0 * c0 + i0 * g0; float hv0 = o0 * tanh_pre2(c0 * L2E2); \
    float i1 = sig_pre(a0[1]), f1 = sig_pre(a1[1]), g1 = tanh_pre2(a2[1]), o1 = sig_pre(a3[1]); \
    c1 = f1 * c1 + i1 * g1; float hv1 = o1 * tanh_pre2(c1 * L2E2); \
    float i2 = sig_pre(a0[2]), f2 = sig_pre(a1[2]), g2 = tanh_pre2(a2[2]), o2 = sig_pre(a3[2]); \
    c2 = f2 * c2 + i2 * g2; float hv2 = o2 * tanh_pre2(c2 * L2E2); \
    float i3 = sig_pre(a0[3]), f3 = sig_pre(a1[3]), g3 = tanh_pre2(a2[3]), o3 = sig_pre(a3[3]); \
    c3 = f3 * c3 + i3 * g3; float hv3 = o3 * tanh_pre2(c3 * L2E2); \
    pk0 = cvtpk(hv0, hv1); \
    pk1 = cvtpk(hv2, hv3); \
    if ((T) < 15) { \
        unsigned short* hp = &hbuf[(T) & 1][qh * 4][colb]; \
        hp[0]   = (unsigned short)pk0; \
        hp[136] = (unsigned short)(pk0 >> 16); \
        hp[272] = (unsigned short)pk1; \
        hp[408] = (unsigned short)(pk1 >> 16); \
        barrier_lgkm(); \
    } }

    STEP(0,  xa0, xa1, xa2, xa3)
    STEP(1,  xb0, xb1, xb2, xb3)
    STEP(2,  xa0, xa1, xa2, xa3)
    STEP(3,  xb0, xb1, xb2, xb3)
    STEP(4,  xa0, xa1, xa2, xa3)
    STEP(5,  xb0, xb1, xb2, xb3)
    STEP(6,  xa0, xa1, xa2, xa3)
    STEP(7,  xb0, xb1, xb2, xb3)
    STEP(8,  xa0, xa1, xa2, xa3)
    STEP(9,  xb0, xb1, xb2, xb3)
    STEP(10, xa0, xa1, xa2, xa3)
    STEP(11, xb0, xb1, xb2, xb3)
    STEP(12, xa0, xa1, xa2, xa3)
    STEP(13, xb0, xb1, xb2, xb3)
    STEP(14, xa0, xa1, xa2, xa3)
    STEP(15, xb0, xb1, xb2, xb3)
#undef STEP
#undef GATH

    unsigned short* ap = agg + (size_t)(base + qh * 4) * HDIM + colb;
    ap[0]   = (unsigned short)pk0;
    ap[128] = (unsigned short)(pk0 >> 16);
    ap[256] = (unsigned short)pk1;
    ap[384] = (unsigned short)(pk1 >> 16);
}

// ---- gemmCA: h_next = relu(agg.wl^T + h.wr^T + bl) + Xih next, 32 nodes ----
__global__ __launch_bounds__(256) void gemmCA_kernel(
        const unsigned short* __restrict__ agg, const unsigned short* __restrict__ hcur,
        const unsigned short* __restrict__ wl, const unsigned short* __restrict__ wr,
        const float* __restrict__ bl, const unsigned short* __restrict__ wih,
        const float* __restrict__ biasc, unsigned short* __restrict__ hnext,
        unsigned short* __restrict__ xihb) {
    __shared__ unsigned short htile[32][136];
    const int lane = threadIdx.x & 63, wv = threadIdx.x >> 6;
    const int cl = lane & 15, qh = lane >> 4, k8 = qh * 8;
    const int mbase = blockIdx.x * 32;

    bf16x8 bA0[4], bA1[4], bH0[4], bH1[4];
#pragma unroll
    for (int kt = 0; kt < 4; ++kt) {
        bA0[kt] = *(const bf16x8*)(agg  + (size_t)(mbase + cl) * HDIM + kt * 32 + k8);
        bA1[kt] = *(const bf16x8*)(agg  + (size_t)(mbase + 16 + cl) * HDIM + kt * 32 + k8);
        bH0[kt] = *(const bf16x8*)(hcur + (size_t)(mbase + cl) * HDIM + kt * 32 + k8);
        bH1[kt] = *(const bf16x8*)(hcur + (size_t)(mbase + 16 + cl) * HDIM + kt * 32 + k8);
    }
#pragma unroll
    for (int nt = 0; nt < 2; ++nt) {
        const int col = wv * 32 + nt * 16 + cl;
        f32x4 acc0 = {0.f, 0.f, 0.f, 0.f}, acc1 = {0.f, 0.f, 0.f, 0.f};
#pragma unroll
        for (int kt = 0; kt < 4; ++kt) {
            bf16x8 w = *(const bf16x8*)(wl + col * HDIM + kt * 32 + k8);
            acc0 = mfma16(bA0[kt], w, acc0);
            acc1 = mfma16(bA1[kt], w, acc1);
        }
#pragma unroll
        for (int kt = 0; kt < 4; ++kt) {
            bf16x8 w = *(const bf16x8*)(wr + col * HDIM + kt * 32 + k8);
            acc0 = mfma16(bH0[kt], w, acc0);
            acc1 = mfma16(bH1[kt], w, acc1);
        }
        float bias = bl[col];
#pragma unroll
        for (int r = 0; r < 4; ++r) {
            unsigned short v0 = f2bf(fmaxf(acc0[r] + bias, 0.f));
            unsigned short v1 = f2bf(fmaxf(acc1[r] + bias, 0.f));
            hnext[(size_t)(mbase + qh * 4 + r) * HDIM + col] = v0;
            hnext[(size_t)(mbase + 16 + qh * 4 + r) * HDIM + col] = v1;
            htile[qh * 4 + r][col] = v0;
            htile[16 + qh * 4 + r][col] = v1;
        }
    }
    __syncthreads();

    phaseA2(htile, wih, biasc, xihb, mbase, cl, qh, k8, wv);
}

// ---- gemmCF: out = agg.wl^T + h.wr^T + bl (f32), 32 nodes ------------------
__global__ __launch_bounds__(256) void gemmCF_kernel(
        const unsigned short* __restrict__ agg, const unsigned short* __restrict__ hcur,
        const unsigned short* __restrict__ wl, const unsigned short* __restrict__ wr,
        const float* __restrict__ bl, float* __restrict__ fout) {
    const int lane = threadIdx.x & 63, wv = threadIdx.x >> 6;
    const int cl = lane & 15, qh = lane >> 4, k8 = qh * 8;
    const int mbase = blockIdx.x * 32;

    bf16x8 bA0[4], bA1[4], bH0[4], bH1[4];
#pragma unroll
    for (int kt = 0; kt < 4; ++kt) {
        bA0[kt] = *(const bf16x8*)(agg  + (size_t)(mbase + cl) * HDIM + kt * 32 + k8);
        bA1[kt] = *(const bf16x8*)(agg  + (size_t)(mbase + 16 + cl) * HDIM + kt * 32 + k8);
        bH0[kt] = *(const bf16x8*)(hcur + (size_t)(mbase + cl) * HDIM + kt * 32 + k8);
        bH1[kt] = *(const bf16x8*)(hcur + (size_t)(mbase + 16 + cl) * HDIM + kt * 32 + k8);
    }
#pragma unroll
    for (int nt = 0; nt < 2; ++nt) {
        const int col = wv * 32 + nt * 16 + cl;
        f32x4 acc0 = {0.f, 0.f, 0.f, 0.f}, acc1 = {0.f, 0.f, 0.f, 0.f};
#pragma unroll
        for (int kt = 0; kt < 4; ++kt) {
            bf16x8 w = *(const bf16x8*)(wl + col * HDIM + kt * 32 + k8);
            acc0 = mfma16(bA0[kt], w, acc0);
            acc1 = mfma16(bA1[kt], w, acc1);
        }
#pragma unroll
        for (int kt = 0; kt < 4; ++kt) {
            bf16x8 w = *(const bf16x8*)(wr + col * HDIM + kt * 32 + k8);
            acc0 = mfma16(bH0[kt], w, acc0);
            acc1 = mfma16(bH1[kt], w, acc1);
        }
        float bias = bl[col];
#pragma unroll
        for (int r = 0; r < 4; ++r) {
            fout[(size_t)(mbase + qh * 4 + r) * HDIM + col] = acc0[r] + bias;
            fout[(size_t)(mbase + 16 + qh * 4 + r) * HDIM + col] = acc1[r] + bias;
        }
    }
}

// ---------------- host ------------------------------------------------------
extern "C" void kernel_launch(void* const* d_in, const int* in_sizes, int n_in,
                              void* d_out, int out_size, void* d_ws, size_t ws_size,
                              hipStream_t stream) {
    (void)in_sizes; (void)n_in; (void)out_size; (void)ws_size;

    const float* x     = (const float*)d_in[0];
    const int*   types = (const int*)d_in[1];
    const int*   esrc  = (const int*)d_in[2];
    const float* emb   = (const float*)d_in[4];

    char* ws = (char*)d_ws;
    unsigned short* hA   = (unsigned short*)ws; ws += (size_t)NN * HDIM * 2;
    unsigned short* hB   = (unsigned short*)ws; ws += (size_t)NN * HDIM * 2;
    unsigned short* agg  = (unsigned short*)ws; ws += (size_t)NN * HDIM * 2;
    unsigned short* xihb = (unsigned short*)ws; ws += (size_t)NN * GDIM * 2;
    unsigned short* wbf  = (unsigned short*)ws; ws += (size_t)3 * 163840 * 2;
    float*          bc   = (float*)ws;          // 3 x 512 f32

    unsigned short *wihb[3], *whhb[3], *wlb[3], *wrb[3];
    float* bcl[3];
    CvtArgs ca;
    for (int l = 0; l < 3; ++l) {
        unsigned short* lb = wbf + (size_t)l * 163840;
        wihb[l] = lb;
        whhb[l] = lb + 65536;
        wlb[l]  = lb + 131072;
        wrb[l]  = lb + 147456;
        bcl[l]  = bc + l * 512;
        ca.wih[l] = (const float*)d_in[5 + 7 * l + 0];
        ca.whh[l] = (const float*)d_in[5 + 7 * l + 1];
        ca.bih[l] = (const float*)d_in[5 + 7 * l + 2];
        ca.bhh[l] = (const float*)d_in[5 + 7 * l + 3];
        ca.wl[l]  = (const float*)d_in[5 + 7 * l + 4];
        ca.wr[l]  = (const float*)d_in[5 + 7 * l + 6];
        ca.dih[l] = wihb[l]; ca.dhh[l] = whhb[l]; ca.dl[l] = wlb[l]; ca.dr[l] = wrb[l];
        ca.dbias[l] = bcl[l];
    }
    cvt_kernel<<<1926, 256, 0, stream>>>(ca);

    gemmA0_kernel<<<NN / 32, 256, 0, stream>>>(x, types, emb, wihb[0], bcl[0], hA, xihb);

    unsigned short* hc = hA;
    unsigned short* hn = hB;
    for (int l = 0; l < 3; ++l) {
        const float* bl = (const float*)d_in[5 + 7 * l + 5];
        lstm_kernel<<<NN / 16, 512, 0, stream>>>(xihb, whhb[l], esrc, agg);
        if (l < 2) {
            gemmCA_kernel<<<NN / 32, 256, 0, stream>>>(
                agg, hc, wlb[l], wrb[l], bl, wihb[l + 1], bcl[l + 1], hn, xihb);
            unsigned short* t = hc; hc = hn; hn = t;
        } else {
            gemmCF_kernel<<<NN / 32, 256, 0, stream>>>(
                agg, hc, wlb[l], wrb[l], bl, (float*)d_out);
        }
    }
}

// Round 13
// 303.854 us; speedup vs baseline: 4.6284x; 4.6284x over previous
//
#include <hip/hip_runtime.h>

#define NN 20000
#define DEG 16
#define HDIM 128
#define GDIM 512

typedef __attribute__((ext_vector_type(8))) short bf16x8;
typedef __attribute__((ext_vector_type(4))) float f32x4;
typedef __attribute__((ext_vector_type(2))) unsigned u32x2;
typedef __attribute__((ext_vector_type(4))) unsigned u32x4;
typedef unsigned long long ull;

#define L2E  1.4426950408889634f
#define L2E2 2.8853900817779268f

__device__ __forceinline__ f32x4 mfma16(bf16x8 a, bf16x8 b, f32x4 c) {
    return __builtin_amdgcn_mfma_f32_16x16x32_bf16(a, b, c, 0, 0, 0);
}

__device__ __forceinline__ unsigned short f2bf(float f) {
    unsigned u = __builtin_bit_cast(unsigned, f);
    u += 0x7FFFu + ((u >> 16) & 1u);
    return (unsigned short)(u >> 16);
}

__device__ __forceinline__ unsigned cvtpk(float lo, float hi) {
    unsigned r;
    asm("v_cvt_pk_bf16_f32 %0, %1, %2" : "=v"(r) : "v"(lo), "v"(hi));
    return r;
}

__device__ __forceinline__ float bfhi(unsigned u) { return __builtin_bit_cast(float, u & 0xFFFF0000u); }
__device__ __forceinline__ float bflo(unsigned u) { return __builtin_bit_cast(float, u << 16); }

__device__ __forceinline__ void barrier_lgkm() {
    asm volatile("s_waitcnt lgkmcnt(0)\ns_barrier" ::: "memory");
}

__device__ __forceinline__ float sig_pre(float x) {     // x pre-scaled by log2e
    return __builtin_amdgcn_rcpf(1.f + __builtin_amdgcn_exp2f(-x));
}
__device__ __forceinline__ float tanh_pre2(float x2) {  // x2 pre-scaled by 2*log2e
    return 1.f - 2.f * __builtin_amdgcn_rcpf(__builtin_amdgcn_exp2f(x2) + 1.f);
}

// ---------------- weight convert + combined bias ----------------------------
// dhh emitted FRAGMENT-CONTIGUOUS: thread (col,qh) finds its 16 bf16x8
// fragments (g,kt) at dhh[col*512 + qh*128 + g*32 + kt*8 + j] — one base
// address + imm offsets 0..240B in the lstm kernel (addressing VALU ~0).
struct CvtArgs {
    const float *wih[3], *whh[3], *wl[3], *wr[3], *bih[3], *bhh[3];
    unsigned short *dih[3], *dhh[3], *dl[3], *dr[3];
    float *dbias[3];
};

__global__ __launch_bounds__(256) void cvt_kernel(CvtArgs a) {
    int l = blockIdx.x / 642, b = blockIdx.x % 642, t = threadIdx.x;
    if (b < 256) {
        int i = b * 256 + t;
        float s = ((i >> 14) == 2) ? L2E2 : L2E;
        a.dih[l][i] = f2bf(a.wih[l][i] * s);
    } else if (b < 512) {                // w_hh -> fragment-contiguous
        int o = (b - 256) * 256 + t;     // o = col*512 + qh*128 + g*32 + kt*8 + j
        int j = o & 7, kt = (o >> 3) & 3, g = (o >> 5) & 3;
        int qh = (o >> 7) & 3, col = (o >> 9) & 127;
        float s = (g == 2) ? L2E2 : L2E;
        a.dhh[l][o] = f2bf(a.whh[l][(g * 128 + col) * 128 + kt * 32 + qh * 8 + j] * s);
    } else if (b < 576) {
        int i = (b - 512) * 256 + t;
        a.dl[l][i] = f2bf(a.wl[l][i]);
    } else if (b < 640) {
        int i = (b - 576) * 256 + t;
        a.dr[l][i] = f2bf(a.wr[l][i]);
    } else {
        int i = (b - 640) * 256 + t;
        float s = ((i >> 7) == 2) ? L2E2 : L2E;
        a.dbias[l][i] = (a.bih[l][i] + a.bhh[l][i]) * s;
    }
}

// ---- phase A (32-node tile): Xih from htile, interleaved bf16 out ----------
__device__ __forceinline__ void phaseA2(const unsigned short (*htile)[136],
        const unsigned short* __restrict__ wih, const float* __restrict__ biasc,
        unsigned short* __restrict__ xihb, int mbase, int cl, int qh, int k8, int wv) {
    bf16x8 a0[4], a1[4];
#pragma unroll
    for (int kt = 0; kt < 4; ++kt) {
        a0[kt] = *(const bf16x8*)(&htile[cl][kt * 32 + k8]);
        a1[kt] = *(const bf16x8*)(&htile[16 + cl][kt * 32 + k8]);
    }
#pragma unroll
    for (int nt = 0; nt < 2; ++nt) {
        const int col = wv * 32 + nt * 16 + cl;
        f32x4 acc0[4], acc1[4];
#pragma unroll
        for (int g = 0; g < 4; ++g) {
            acc0[g] = (f32x4){0.f, 0.f, 0.f, 0.f};
            acc1[g] = (f32x4){0.f, 0.f, 0.f, 0.f};
        }
#pragma unroll
        for (int g = 0; g < 4; ++g)
#pragma unroll
            for (int kt = 0; kt < 4; ++kt) {
                bf16x8 b = *(const bf16x8*)(wih + (g * 128 + col) * HDIM + kt * 32 + k8);
                acc0[g] = mfma16(a0[kt], b, acc0[g]);
                acc1[g] = mfma16(a1[kt], b, acc1[g]);
            }
        float bias[4];
#pragma unroll
        for (int g = 0; g < 4; ++g) bias[g] = biasc[g * 128 + col];
#pragma unroll
        for (int r = 0; r < 4; ++r) {
            unsigned p0 = cvtpk(acc0[0][r] + bias[0], acc0[1][r] + bias[1]);
            unsigned p1 = cvtpk(acc0[2][r] + bias[2], acc0[3][r] + bias[3]);
            *(ull*)(xihb + (size_t)(mbase + qh * 4 + r) * GDIM + col * 4) =
                (ull)p0 | ((ull)p1 << 32);
            unsigned q0 = cvtpk(acc1[0][r] + bias[0], acc1[1][r] + bias[1]);
            unsigned q1 = cvtpk(acc1[2][r] + bias[2], acc1[3][r] + bias[3]);
            *(ull*)(xihb + (size_t)(mbase + 16 + qh * 4 + r) * GDIM + col * 4) =
                (ull)q0 | ((ull)q1 << 32);
        }
    }
}

// ---- gemmA0: h0 = concat(x, emb[type]) (bf16) + Xih layer 0, 32 nodes ------
__global__ __launch_bounds__(256) void gemmA0_kernel(
        const float* __restrict__ x, const int* __restrict__ types,
        const float* __restrict__ emb, const unsigned short* __restrict__ wih,
        const float* __restrict__ biasc, unsigned short* __restrict__ h0,
        unsigned short* __restrict__ xihb) {
    __shared__ unsigned short htile[32][136];
    const int tid = threadIdx.x;
    const int lane = tid & 63, wv = tid >> 6;
    const int cl = lane & 15, qh = lane >> 4, k8 = qh * 8;
    const int mbase = blockIdx.x * 32;

    const int row = tid >> 3, c0 = (tid & 7) * 16;
    f32x4 u[4];
    if (c0 < 96) {
#pragma unroll
        for (int j = 0; j < 4; ++j)
            u[j] = *(const f32x4*)(x + (size_t)(mbase + row) * 96 + c0 + 4 * j);
    } else {
        int ty = types[mbase + row];
#pragma unroll
        for (int j = 0; j < 4; ++j)
            u[j] = *(const f32x4*)(emb + ty * 32 + (c0 - 96) + 4 * j);
    }
    u32x4 pk, pk2;
    pk[0]  = cvtpk(u[0][0], u[0][1]); pk[1]  = cvtpk(u[0][2], u[0][3]);
    pk[2]  = cvtpk(u[1][0], u[1][1]); pk[3]  = cvtpk(u[1][2], u[1][3]);
    pk2[0] = cvtpk(u[2][0], u[2][1]); pk2[1] = cvtpk(u[2][2], u[2][3]);
    pk2[2] = cvtpk(u[3][0], u[3][1]); pk2[3] = cvtpk(u[3][2], u[3][3]);
    *(u32x4*)(&htile[row][c0]) = pk;
    *(u32x4*)(&htile[row][c0 + 8]) = pk2;
    *(u32x4*)(h0 + (size_t)(mbase + row) * HDIM + c0) = pk;
    *(u32x4*)(h0 + (size_t)(mbase + row) * HDIM + c0 + 8) = pk2;
    __syncthreads();

    phaseA2(htile, wih, biasc, xihb, mbase, cl, qh, k8, wv);
}

// ---------------- fused per-node LSTM ---------------------------------------
// EXACT round-5 skeleton (78 µs, VGPR 60, stable): 512 thr / 8 waves, 16
// nodes/block, launch_bounds(512,2), w-loads referenced inline in the MFMA
// group. ONLY change: whhf is fragment-contiguous, so the per-step reloads
// (forced by the barrier clobber) share ONE address register + imm offsets.
__global__ __launch_bounds__(512, 2) void lstm_kernel(
        const unsigned short* __restrict__ xihb, const unsigned short* __restrict__ whhf,
        const int* __restrict__ esrc, unsigned short* __restrict__ agg) {
    __shared__ unsigned short hbuf[2][16][136];   // +8 pad
    __shared__ unsigned srcs_t[256];              // [t][node], pre-shifted <<10

    const int tid = threadIdx.x;
    const int lane = tid & 63, wv = tid >> 6;
    const int cl = lane & 15, qh = lane >> 4, k8 = qh * 8;
    const int colb = wv * 16 + cl;
    const int base = blockIdx.x * 16;

    if (tid < 256)
        srcs_t[(tid & 15) * 16 + (tid >> 4)] = ((unsigned)esrc[base * DEG + tid]) << 10;

    const unsigned short* wp = whhf + (size_t)colb * 512 + qh * 128;
#define LDW(kt, g) (*(const bf16x8*)(wp + (g) * 32 + (kt) * 8))
    bf16x8 w00 = LDW(0,0), w01 = LDW(0,1), w02 = LDW(0,2), w03 = LDW(0,3);
    bf16x8 w10 = LDW(1,0), w11 = LDW(1,1), w12 = LDW(1,2), w13 = LDW(1,3);
    bf16x8 w20 = LDW(2,0), w21 = LDW(2,1), w22 = LDW(2,2), w23 = LDW(2,3);
    bf16x8 w30 = LDW(3,0), w31 = LDW(3,1), w32 = LDW(3,2), w33 = LDW(3,3);
#undef LDW
    __syncthreads();

    const char* xp = (const char*)xihb + (size_t)colb * 8u;
    float c0 = 0.f, c1 = 0.f, c2 = 0.f, c3 = 0.f;
    unsigned pk0 = 0, pk1 = 0;
    ull xa0, xa1, xa2, xa3, xb0, xb1, xb2, xb3;

#define GATH(T, X0, X1, X2, X3) { \
    u32x4 sv = *(const u32x4*)&srcs_t[(T) * 16 + qh * 4]; \
    X0 = *(const ull*)(xp + sv[0]); \
    X1 = *(const ull*)(xp + sv[1]); \
    X2 = *(const ull*)(xp + sv[2]); \
    X3 = *(const ull*)(xp + sv[3]); }

    GATH(0, xa0, xa1, xa2, xa3)
    GATH(1, xb0, xb1, xb2, xb3)

#define STEP(T, X0, X1, X2, X3) { \
    f32x4 a0, a1, a2, a3; \
    { unsigned lo = (unsigned)X0, hi = (unsigned)(X0 >> 32); \
      a0[0] = bflo(lo); a1[0] = bfhi(lo); a2[0] = bflo(hi); a3[0] = bfhi(hi); } \
    { unsigned lo = (unsigned)X1, hi = (unsigned)(X1 >> 32); \
      a0[1] = bflo(lo); a1[1] = bfhi(lo); a2[1] = bflo(hi); a3[1] = bfhi(hi); } \
    { unsigned lo = (unsigned)X2, hi = (unsigned)(X2 >> 32); \
      a0[2] = bflo(lo); a1[2] = bfhi(lo); a2[2] = bflo(hi); a3[2] = bfhi(hi); } \
    { unsigned lo = (unsigned)X3, hi = (unsigned)(X3 >> 32); \
      a0[3] = bflo(lo); a1[3] = bfhi(lo); a2[3] = bflo(hi); a3[3] = bfhi(hi); } \
    if ((T) < 14) { GATH((T) + 2, X0, X1, X2, X3) } \
    if ((T) > 0) { \
        const unsigned short* hrow = &hbuf[((T) + 1) & 1][cl][k8]; \
        bf16x8 h0 = *(const bf16x8*)(hrow); \
        bf16x8 h1 = *(const bf16x8*)(hrow + 32); \
        bf16x8 h2 = *(const bf16x8*)(hrow + 64); \
        bf16x8 h3 = *(const bf16x8*)(hrow + 96); \
        a0 = mfma16(h0, w00, a0); a0 = mfma16(h1, w10, a0); \
        a0 = mfma16(h2, w20, a0); a0 = mfma16(h3, w30, a0); \
        a1 = mfma16(h0, w01, a1); a1 = mfma16(h1, w11, a1); \
        a1 = mfma16(h2, w21, a1); a1 = mfma16(h3, w31, a1); \
        a2 = mfma16(h0, w02, a2); a2 = mfma16(h1, w12, a2); \
        a2 = mfma16(h2, w22, a2); a2 = mfma16(h3, w32, a2); \
        a3 = mfma16(h0, w03, a3); a3 = mfma16(h1, w13, a3); \
        a3 = mfma16(h2, w23, a3); a3 = mfma16(h3, w33, a3); \
    } \
    float i0 = sig_pre(a0[0]), f0 = sig_pre(a1[0]), g0 = tanh_pre2(a2[0]), o0 = sig_pre(a3[0]); \
    c0 = f0 * c0 + i0 * g0; float hv0 = o0 * tanh_pre2(c0 * L2E2); \
    float i1 = sig_pre(a0[1]), f1 = sig_pre(a1[1]), g1 = tanh_pre2(a2[1]), o1 = sig_pre(a3[1]); \
    c1 = f1 * c1 + i1 * g1; float hv1 = o1 * tanh_pre2(c1 * L2E2); \
    float i2 = sig_pre(a0[2]), f2 = sig_pre(a1[2]), g2 = tanh_pre2(a2[2]), o2 = sig_pre(a3[2]); \
    c2 = f2 * c2 + i2 * g2; float hv2 = o2 * tanh_pre2(c2 * L2E2); \
    float i3 = sig_pre(a0[3]), f3 = sig_pre(a1[3]), g3 = tanh_pre2(a2[3]), o3 = sig_pre(a3[3]); \
    c3 = f3 * c3 + i3 * g3; float hv3 = o3 * tanh_pre2(c3 * L2E2); \
    pk0 = cvtpk(hv0, hv1); \
    pk1 = cvtpk(hv2, hv3); \
    if ((T) < 15) { \
        unsigned short* hp = &hbuf[(T) & 1][qh * 4][colb]; \
        hp[0]   = (unsigned short)pk0; \
        hp[136] = (unsigned short)(pk0 >> 16); \
        hp[272] = (unsigned short)pk1; \
        hp[408] = (unsigned short)(pk1 >> 16); \
        barrier_lgkm(); \
    } }

    STEP(0,  xa0, xa1, xa2, xa3)
    STEP(1,  xb0, xb1, xb2, xb3)
    STEP(2,  xa0, xa1, xa2, xa3)
    STEP(3,  xb0, xb1, xb2, xb3)
    STEP(4,  xa0, xa1, xa2, xa3)
    STEP(5,  xb0, xb1, xb2, xb3)
    STEP(6,  xa0, xa1, xa2, xa3)
    STEP(7,  xb0, xb1, xb2, xb3)
    STEP(8,  xa0, xa1, xa2, xa3)
    STEP(9,  xb0, xb1, xb2, xb3)
    STEP(10, xa0, xa1, xa2, xa3)
    STEP(11, xb0, xb1, xb2, xb3)
    STEP(12, xa0, xa1, xa2, xa3)
    STEP(13, xb0, xb1, xb2, xb3)
    STEP(14, xa0, xa1, xa2, xa3)
    STEP(15, xb0, xb1, xb2, xb3)
#undef STEP
#undef GATH

    unsigned short* ap = agg + (size_t)(base + qh * 4) * HDIM + colb;
    ap[0]   = (unsigned short)pk0;
    ap[128] = (unsigned short)(pk0 >> 16);
    ap[256] = (unsigned short)pk1;
    ap[384] = (unsigned short)(pk1 >> 16);
}

// ---- gemmCA: h_next = relu(agg.wl^T + h.wr^T + bl) + Xih next, 32 nodes ----
__global__ __launch_bounds__(256) void gemmCA_kernel(
        const unsigned short* __restrict__ agg, const unsigned short* __restrict__ hcur,
        const unsigned short* __restrict__ wl, const unsigned short* __restrict__ wr,
        const float* __restrict__ bl, const unsigned short* __restrict__ wih,
        const float* __restrict__ biasc, unsigned short* __restrict__ hnext,
        unsigned short* __restrict__ xihb) {
    __shared__ unsigned short htile[32][136];
    const int lane = threadIdx.x & 63, wv = threadIdx.x >> 6;
    const int cl = lane & 15, qh = lane >> 4, k8 = qh * 8;
    const int mbase = blockIdx.x * 32;

    bf16x8 bA0[4], bA1[4], bH0[4], bH1[4];
#pragma unroll
    for (int kt = 0; kt < 4; ++kt) {
        bA0[kt] = *(const bf16x8*)(agg  + (size_t)(mbase + cl) * HDIM + kt * 32 + k8);
        bA1[kt] = *(const bf16x8*)(agg  + (size_t)(mbase + 16 + cl) * HDIM + kt * 32 + k8);
        bH0[kt] = *(const bf16x8*)(hcur + (size_t)(mbase + cl) * HDIM + kt * 32 + k8);
        bH1[kt] = *(const bf16x8*)(hcur + (size_t)(mbase + 16 + cl) * HDIM + kt * 32 + k8);
    }
#pragma unroll
    for (int nt = 0; nt < 2; ++nt) {
        const int col = wv * 32 + nt * 16 + cl;
        f32x4 acc0 = {0.f, 0.f, 0.f, 0.f}, acc1 = {0.f, 0.f, 0.f, 0.f};
#pragma unroll
        for (int kt = 0; kt < 4; ++kt) {
            bf16x8 w = *(const bf16x8*)(wl + col * HDIM + kt * 32 + k8);
            acc0 = mfma16(bA0[kt], w, acc0);
            acc1 = mfma16(bA1[kt], w, acc1);
        }
#pragma unroll
        for (int kt = 0; kt < 4; ++kt) {
            bf16x8 w = *(const bf16x8*)(wr + col * HDIM + kt * 32 + k8);
            acc0 = mfma16(bH0[kt], w, acc0);
            acc1 = mfma16(bH1[kt], w, acc1);
        }
        float bias = bl[col];
#pragma unroll
        for (int r = 0; r < 4; ++r) {
            unsigned short v0 = f2bf(fmaxf(acc0[r] + bias, 0.f));
            unsigned short v1 = f2bf(fmaxf(acc1[r] + bias, 0.f));
            hnext[(size_t)(mbase + qh * 4 + r) * HDIM + col] = v0;
            hnext[(size_t)(mbase + 16 + qh * 4 + r) * HDIM + col] = v1;
            htile[qh * 4 + r][col] = v0;
            htile[16 + qh * 4 + r][col] = v1;
        }
    }
    __syncthreads();

    phaseA2(htile, wih, biasc, xihb, mbase, cl, qh, k8, wv);
}

// ---- gemmCF: out = agg.wl^T + h.wr^T + bl (f32), 32 nodes ------------------
__global__ __launch_bounds__(256) void gemmCF_kernel(
        const unsigned short* __restrict__ agg, const unsigned short* __restrict__ hcur,
        const unsigned short* __restrict__ wl, const unsigned short* __restrict__ wr,
        const float* __restrict__ bl, float* __restrict__ fout) {
    const int lane = threadIdx.x & 63, wv = threadIdx.x >> 6;
    const int cl = lane & 15, qh = lane >> 4, k8 = qh * 8;
    const int mbase = blockIdx.x * 32;

    bf16x8 bA0[4], bA1[4], bH0[4], bH1[4];
#pragma unroll
    for (int kt = 0; kt < 4; ++kt) {
        bA0[kt] = *(const bf16x8*)(agg  + (size_t)(mbase + cl) * HDIM + kt * 32 + k8);
        bA1[kt] = *(const bf16x8*)(agg  + (size_t)(mbase + 16 + cl) * HDIM + kt * 32 + k8);
        bH0[kt] = *(const bf16x8*)(hcur + (size_t)(mbase + cl) * HDIM + kt * 32 + k8);
        bH1[kt] = *(const bf16x8*)(hcur + (size_t)(mbase + 16 + cl) * HDIM + kt * 32 + k8);
    }
#pragma unroll
    for (int nt = 0; nt < 2; ++nt) {
        const int col = wv * 32 + nt * 16 + cl;
        f32x4 acc0 = {0.f, 0.f, 0.f, 0.f}, acc1 = {0.f, 0.f, 0.f, 0.f};
#pragma unroll
        for (int kt = 0; kt < 4; ++kt) {
            bf16x8 w = *(const bf16x8*)(wl + col * HDIM + kt * 32 + k8);
            acc0 = mfma16(bA0[kt], w, acc0);
            acc1 = mfma16(bA1[kt], w, acc1);
        }
#pragma unroll
        for (int kt = 0; kt < 4; ++kt) {
            bf16x8 w = *(const bf16x8*)(wr + col * HDIM + kt * 32 + k8);
            acc0 = mfma16(bH0[kt], w, acc0);
            acc1 = mfma16(bH1[kt], w, acc1);
        }
        float bias = bl[col];
#pragma unroll
        for (int r = 0; r < 4; ++r) {
            fout[(size_t)(mbase + qh * 4 + r) * HDIM + col] = acc0[r] + bias;
            fout[(size_t)(mbase + 16 + qh * 4 + r) * HDIM + col] = acc1[r] + bias;
        }
    }
}

// ---------------- host ------------------------------------------------------
extern "C" void kernel_launch(void* const* d_in, const int* in_sizes, int n_in,
                              void* d_out, int out_size, void* d_ws, size_t ws_size,
                              hipStream_t stream) {
    (void)in_sizes; (void)n_in; (void)out_size; (void)ws_size;

    const float* x     = (const float*)d_in[0];
    const int*   types = (const int*)d_in[1];
    const int*   esrc  = (const int*)d_in[2];
    const float* emb   = (const float*)d_in[4];

    char* ws = (char*)d_ws;
    unsigned short* hA   = (unsigned short*)ws; ws += (size_t)NN * HDIM * 2;
    unsigned short* hB   = (unsigned short*)ws; ws += (size_t)NN * HDIM * 2;
    unsigned short* agg  = (unsigned short*)ws; ws += (size_t)NN * HDIM * 2;
    unsigned short* xihb = (unsigned short*)ws; ws += (size_t)NN * GDIM * 2;
    unsigned short* wbf  = (unsigned short*)ws; ws += (size_t)3 * 163840 * 2;
    float*          bc   = (float*)ws;          // 3 x 512 f32

    unsigned short *wihb[3], *whhb[3], *wlb[3], *wrb[3];
    float* bcl[3];
    CvtArgs ca;
    for (int l = 0; l < 3; ++l) {
        unsigned short* lb = wbf + (size_t)l * 163840;
        wihb[l] = lb;
        whhb[l] = lb + 65536;
        wlb[l]  = lb + 131072;
        wrb[l]  = lb + 147456;
        bcl[l]  = bc + l * 512;
        ca.wih[l] = (const float*)d_in[5 + 7 * l + 0];
        ca.whh[l] = (const float*)d_in[5 + 7 * l + 1];
        ca.bih[l] = (const float*)d_in[5 + 7 * l + 2];
        ca.bhh[l] = (const float*)d_in[5 + 7 * l + 3];
        ca.wl[l]  = (const float*)d_in[5 + 7 * l + 4];
        ca.wr[l]  = (const float*)d_in[5 + 7 * l + 6];
        ca.dih[l] = wihb[l]; ca.dhh[l] = whhb[l]; ca.dl[l] = wlb[l]; ca.dr[l] = wrb[l];
        ca.dbias[l] = bcl[l];
    }
    cvt_kernel<<<1926, 256, 0, stream>>>(ca);

    gemmA0_kernel<<<NN / 32, 256, 0, stream>>>(x, types, emb, wihb[0], bcl[0], hA, xihb);

    unsigned short* hc = hA;
    unsigned short* hn = hB;
    for (int l = 0; l < 3; ++l) {
        const float* bl = (const float*)d_in[5 + 7 * l + 5];
        lstm_kernel<<<NN / 16, 512, 0, stream>>>(xihb, whhb[l], esrc, agg);
        if (l < 2) {
            gemmCA_kernel<<<NN / 32, 256, 0, stream>>>(
                agg, hc, wlb[l], wrb[l], bl, wihb[l + 1], bcl[l + 1], hn, xihb);
            unsigned short* t = hc; hc = hn; hn = t;
        } else {
            gemmCF_kernel<<<NN / 32, 256, 0, stream>>>(
                agg, hc, wlb[l], wrb[l], bl, (float*)d_out);
        }
    }
}